// Round 13
// baseline (263.935 us; speedup 1.0000x reference)
//
#include <hip/hip_runtime.h>
#include <hip/hip_fp16.h>
#include <math.h>

#define N_NODES 50000
#define N_EDGES 800000
#define N_GRAPHS 64
#define L2E 1.44269504f

#if __has_builtin(__builtin_amdgcn_fdot2)
#define HAS_FDOT2 1
typedef _Float16 h2_t __attribute__((ext_vector_type(2)));
#else
#define HAS_FDOT2 0
#endif

typedef _Float16 f16x8 __attribute__((ext_vector_type(8)));
typedef float f32x4 __attribute__((ext_vector_type(4)));

__device__ __forceinline__ float elu1(float v){ return v > 0.f ? v : expm1f(v); }

__device__ __forceinline__ __half2 bcast_h2(float e){
    // pack-convert (e,e) f32 -> 2xfp16 in one VALU op (RTZ; e>=0 so tiny down-bias)
    return __builtin_bit_cast(__half2, __builtin_amdgcn_cvt_pkrtz(e, e));
}

// folded logit partial: sum over 8 ch of (A6*u + A4*|u|), u = q + r (fp16 pk).
// A6 = 0.6*log2e*att, A4 = 0.4*log2e*att  ->  log2-domain logit partial.
__device__ __forceinline__ float pkdot(float4 q, const __half2* r2,
        const __half2* A6, const __half2* A4){
    const __half2* qh = (const __half2*)&q;
    float p = 0.f;
#if HAS_FDOT2
    #pragma unroll
    for (int i=0;i<4;i++){
        __half2 u = __hadd2(qh[i], r2[i]);
        __half2 ua = __builtin_bit_cast(__half2,
            __builtin_bit_cast(unsigned, u) & 0x7FFF7FFFu);
        p = __builtin_amdgcn_fdot2(__builtin_bit_cast(h2_t,u),
                                   __builtin_bit_cast(h2_t,A6[i]), p, false);
        p = __builtin_amdgcn_fdot2(__builtin_bit_cast(h2_t,ua),
                                   __builtin_bit_cast(h2_t,A4[i]), p, false);
    }
#else
    #pragma unroll
    for (int i=0;i<4;i++){
        float2 qf = __half22float2(qh[i]);
        float2 rf = __half22float2(r2[i]);
        float2 s6 = __half22float2(A6[i]);
        float2 s4 = __half22float2(A4[i]);
        float u0 = qf.x + rf.x, u1 = qf.y + rf.y;
        p = fmaf(s6.x, u0, fmaf(s4.x, fabsf(u0), p));
        p = fmaf(s6.y, u1, fmaf(s4.y, fabsf(u1), p));
    }
#endif
    return p;
}

// ---- prep: blocks [0,782): dst histogram WITH rank capture (contended
// atomics start FIRST, conversions overlap behind); [782,3907): x f32->fp16;
// [3907,4163): weight cvt+transpose (+ pooled zero). deg zeroed by memset.
__global__ __launch_bounds__(256) void k_prep(const float* __restrict__ x,
        const float* __restrict__ Wl1, const float* __restrict__ Wr1,
        const float* __restrict__ Wl2, const float* __restrict__ Wr2,
        const int* __restrict__ ei,
        __half* __restrict__ xh, __half* __restrict__ Wt1, __half* __restrict__ Wt2,
        int* __restrict__ deg, int* __restrict__ ranks, float* __restrict__ pooled){
    int t = threadIdx.x, bk = blockIdx.x;
    if (bk < 782){
        int e4 = bk*256 + t;
        if (e4 < N_EDGES/4){
            int4 d = ((const int4*)(ei + N_EDGES))[e4];
            int4 r;
            r.x = atomicAdd(&deg[d.x],1);
            r.y = atomicAdd(&deg[d.y],1);
            r.z = atomicAdd(&deg[d.z],1);
            r.w = atomicAdd(&deg[d.w],1);
            ((int4*)ranks)[e4] = r;            // coalesced
        }
    } else if (bk < 3907){
        int idx = (bk-782)*256 + t;            // float4 index, 800000 total
        float4 v = ((const float4*)x)[idx];
        __half2* dst = (__half2*)xh + (size_t)idx*2;
        dst[0] = __floats2half2_rn(v.x, v.y);
        dst[1] = __floats2half2_rn(v.z, v.w);
    } else {
        int elem = (bk-3907)*256 + t;          // 0..65535
        if (elem < 32768){
            int c = elem >> 6, k = elem & 63;  // Wt1[c][k], c in [0,512)
            float v = (c < 256) ? Wl1[k*256 + c] : Wr1[k*256 + (c-256)];
            Wt1[elem] = __float2half(v);
        } else {
            int e2 = elem - 32768;
            int c = e2 >> 8, k = e2 & 255;     // Wt2[c][k], c in [0,128)
            float v = (c < 64) ? Wl2[k*64 + c] : Wr2[k*64 + (c-64)];
            Wt2[e2] = __float2half(v);
        }
        if (elem < N_GRAPHS*64) pooled[elem] = 0.f;
    }
}

__global__ __launch_bounds__(1024) void k_scan_a(const int* __restrict__ deg,
        int* __restrict__ rowptr, int* __restrict__ partial){
    __shared__ int s[1024];
    int t = threadIdx.x; int i = blockIdx.x*1024 + t;
    int v = (i < N_NODES) ? deg[i] : 0;
    s[t] = v; __syncthreads();
    for (int off=1; off<1024; off<<=1){
        int add = (t>=off) ? s[t-off] : 0;
        __syncthreads();
        s[t] += add;
        __syncthreads();
    }
    if (i < N_NODES) rowptr[i] = s[t] - v;
    if (t == 1023) partial[blockIdx.x] = s[1023];
}

__global__ __launch_bounds__(1024) void k_scan_c(int* __restrict__ rowptr,
        const int* __restrict__ partial){
    __shared__ int base;
    if (threadIdx.x == 0){
        int run = 0;
        for (int bk=0; bk<(int)blockIdx.x; bk++) run += partial[bk];
        base = run;
    }
    __syncthreads();
    int i = blockIdx.x*1024 + threadIdx.x;
    if (i < N_NODES){
        rowptr[i] += base;
    } else if (i == N_NODES){
        rowptr[N_NODES] = N_EDGES;
    }
}

// ---- mm1 (+ atomic-free scatter on blockIdx.y==0 so it dispatches FIRST):
// xh [N,64] fp16 @ Wt1^T -> xl1h|xr1h [N,256] fp16, MFMA 16x16x32.
// cg loop inside block: xh read ONCE; per-wave 16x128 C tile staged in LDS.
__global__ __launch_bounds__(256) void k_mm1(const __half* __restrict__ xh,
        const __half* __restrict__ Wt1,
        __half* __restrict__ xl1h, __half* __restrict__ xr1h,
        const int* __restrict__ ei, const int* __restrict__ ranks,
        const int* __restrict__ rowptr, int* __restrict__ srcs){
    if (blockIdx.y == 0){
        int e4 = blockIdx.x*256 + threadIdx.x;
        if (e4 < N_EDGES/4){
            int4 sv = ((const int4*)ei)[e4];
            int4 dv = ((const int4*)(ei + N_EDGES))[e4];
            int4 rv = ((const int4*)ranks)[e4];
            __builtin_nontemporal_store(sv.x, &srcs[rowptr[dv.x] + rv.x]);
            __builtin_nontemporal_store(sv.y, &srcs[rowptr[dv.y] + rv.y]);
            __builtin_nontemporal_store(sv.z, &srcs[rowptr[dv.z] + rv.z]);
            __builtin_nontemporal_store(sv.w, &srcs[rowptr[dv.w] + rv.w]);
        }
        return;
    }
    __shared__ __half lds[4][16*136];
    int w = threadIdx.x >> 6, l = threadIdx.x & 63;
    int r0 = blockIdx.x*64 + w*16;
    int lr = l & 15, lk = l >> 4, lk4 = lk*4;
    int ar = r0 + lr; if (ar >= N_NODES) ar = N_NODES-1;
    const __half* arow = xh + (size_t)ar*64;
    f16x8 a0 = *(const f16x8*)(arow + lk*8);
    f16x8 a1 = *(const f16x8*)(arow + 32 + lk*8);
    #pragma unroll
    for (int cg=0; cg<4; cg++){
        f32x4 acc[8];
        #pragma unroll
        for (int ct=0; ct<8; ct++) acc[ct] = (f32x4){0.f,0.f,0.f,0.f};
        #pragma unroll
        for (int ct=0; ct<8; ct++){
            int col = cg*128 + ct*16 + lr;
            const __half* brow = Wt1 + (size_t)col*64;
            f16x8 b0 = *(const f16x8*)(brow + lk*8);
            f16x8 b1 = *(const f16x8*)(brow + 32 + lk*8);
            acc[ct] = __builtin_amdgcn_mfma_f32_16x16x32_f16(a0, b0, acc[ct], 0,0,0);
            acc[ct] = __builtin_amdgcn_mfma_f32_16x16x32_f16(a1, b1, acc[ct], 0,0,0);
        }
        #pragma unroll
        for (int ct=0; ct<8; ct++){
            #pragma unroll
            for (int i=0;i<4;i++)
                lds[w][(lk4+i)*136 + ct*16 + lr] = __float2half(acc[ct][i]);
        }
        __half* base = (cg < 2) ? xl1h : xr1h;
        int cbase = (cg & 1)*128;
        #pragma unroll
        for (int rr=0; rr<4; rr++){
            int row = rr*4 + lk;
            float4 v = *(const float4*)&lds[w][row*136 + lr*8];
            int grow = r0 + row;
            if (grow < N_NODES)
                *(float4*)&base[(size_t)grow*256 + cbase + lr*8] = v;
        }
    }
}

// ---- mm2: h1h [N,256] fp16 @ Wt2^T -> xl2h|xr2h [N,64] fp16
// cg loop inside block: h1h read ONCE; per-wave 16x64 tile staged in LDS.
__global__ __launch_bounds__(256) void k_mm2(const __half* __restrict__ h1h,
        const __half* __restrict__ Wt2,
        __half* __restrict__ xl2h, __half* __restrict__ xr2h){
    __shared__ __half lds[4][16*72];
    int w = threadIdx.x >> 6, l = threadIdx.x & 63;
    int r0 = blockIdx.x*64 + w*16;
    int lr = l & 15, lk = l >> 4, lk4 = lk*4;
    int ar = r0 + lr; if (ar >= N_NODES) ar = N_NODES-1;
    const __half* arow = h1h + (size_t)ar*256;
    f16x8 a[8];
    #pragma unroll
    for (int ks=0; ks<8; ks++) a[ks] = *(const f16x8*)(arow + ks*32 + lk*8);
    #pragma unroll
    for (int cg=0; cg<2; cg++){
        f32x4 acc[4];
        #pragma unroll
        for (int ct=0; ct<4; ct++) acc[ct] = (f32x4){0.f,0.f,0.f,0.f};
        #pragma unroll
        for (int ks=0; ks<8; ks++){
            #pragma unroll
            for (int ct=0; ct<4; ct++){
                int col = cg*64 + ct*16 + lr;
                f16x8 bf = *(const f16x8*)(Wt2 + (size_t)col*256 + ks*32 + lk*8);
                acc[ct] = __builtin_amdgcn_mfma_f32_16x16x32_f16(a[ks], bf, acc[ct], 0,0,0);
            }
        }
        #pragma unroll
        for (int ct=0; ct<4; ct++){
            #pragma unroll
            for (int i=0;i<4;i++)
                lds[w][(lk4+i)*72 + ct*16 + lr] = __float2half(acc[ct][i]);
        }
        __half* base = (cg == 0) ? xl2h : xr2h;
        #pragma unroll
        for (int rr=0; rr<2; rr++){
            int row = rr*8 + (l>>3);
            float4 v = *(const float4*)&lds[w][row*72 + (l&7)*8];
            int grow = r0 + row;
            if (grow < N_NODES)
                *(float4*)&base[(size_t)grow*64 + (l&7)*8] = v;
        }
    }
}

// ---- fused GAT layer 1: wave per node, 4/block. 32 lanes/edge x 8 ch;
// 2 slots x 2 unroll = 4 edges in flight. 32-bit gather offsets.
__global__ __launch_bounds__(256) void k_gat1(const __half* __restrict__ xlh,
        const __half* __restrict__ xrh, const int* __restrict__ srcs,
        const int* __restrict__ rowptr, const float* __restrict__ att,
        const float* __restrict__ b, __half* __restrict__ h1h){
    int w = threadIdx.x >> 6, l = threadIdx.x & 63;
    int n = blockIdx.x*4 + w;
    int g = l >> 5, sub = l & 31;
    const float4* xh4 = (const float4*)xlh;   // 32 f4 per row
    float4 rq = *(const float4*)(xrh + (size_t)n*256 + sub*8);
    __half2 r2[4];
    { const __half2* rh = (const __half2*)&rq;
      r2[0]=rh[0]; r2[1]=rh[1]; r2[2]=rh[2]; r2[3]=rh[3]; }
    float4 A0v = *(const float4*)(att + sub*8);
    float4 A1v = *(const float4*)(att + sub*8 + 4);
    const float C6 = 0.6f*L2E, C4 = 0.4f*L2E;
    __half2 A6[4] = { __floats2half2_rn(A0v.x*C6, A0v.y*C6),
                      __floats2half2_rn(A0v.z*C6, A0v.w*C6),
                      __floats2half2_rn(A1v.x*C6, A1v.y*C6),
                      __floats2half2_rn(A1v.z*C6, A1v.w*C6) };
    __half2 A4[4] = { __floats2half2_rn(A0v.x*C4, A0v.y*C4),
                      __floats2half2_rn(A0v.z*C4, A0v.w*C4),
                      __floats2half2_rn(A1v.x*C4, A1v.y*C4),
                      __floats2half2_rn(A1v.z*C4, A1v.w*C4) };
    const __half2 Z2 = __floats2half2_rn(0.f, 0.f);
    float accf[8];
    #pragma unroll
    for (int c=0;c<8;c++) accf[c]=0.f;
    float dacc = 0.f;
    int beg = rowptr[n], end = rowptr[n+1];

    auto body = [&](int j, bool checked){
        int j0=j+g, j1=j+2+g, j2=j+4+g, j3=j+6+g;
        bool c0=true, c1=true, c2=true, c3=true;
        if (checked){
            c0 = j0<end; c1 = j1<end; c2 = j2<end; c3 = j3<end;
            j0 = c0?j0:beg; j1 = c1?j1:beg; j2 = c2?j2:beg; j3 = c3?j3:beg;
        }
        int s0 = srcs[j0], s1 = srcs[j1], s2 = srcs[j2], s3 = srcs[j3];
        float4 q0 = xh4[(unsigned)(s0*32 + sub)];
        float4 q1 = xh4[(unsigned)(s1*32 + sub)];
        float4 q2 = xh4[(unsigned)(s2*32 + sub)];
        float4 q3 = xh4[(unsigned)(s3*32 + sub)];
        float p0 = pkdot(q0, r2, A6, A4);
        float p1 = pkdot(q1, r2, A6, A4);
        float p2 = pkdot(q2, r2, A6, A4);
        float p3 = pkdot(q3, r2, A6, A4);
        #pragma unroll
        for (int off=1; off<8; off<<=1){
            p0 += __shfl_xor(p0, off);
            p1 += __shfl_xor(p1, off);
            p2 += __shfl_xor(p2, off);
            p3 += __shfl_xor(p3, off);
        }
        float e0 = exp2f(p0), e1 = exp2f(p1), e2 = exp2f(p2), e3 = exp2f(p3);
        if (checked){
            e0 = c0?e0:0.f; e1 = c1?e1:0.f; e2 = c2?e2:0.f; e3 = c3?e3:0.f;
        }
        __half2 E0 = bcast_h2(e0);
        __half2 E1 = bcast_h2(e1);
        __half2 E2 = bcast_h2(e2);
        __half2 E3 = bcast_h2(e3);
        const __half2* q0h = (const __half2*)&q0;
        const __half2* q1h = (const __half2*)&q1;
        const __half2* q2h = (const __half2*)&q2;
        const __half2* q3h = (const __half2*)&q3;
        #pragma unroll
        for (int i=0;i<4;i++){
            __half2 a16 = __hfma2(E0, q0h[i], Z2);
            a16 = __hfma2(E1, q1h[i], a16);
            a16 = __hfma2(E2, q2h[i], a16);
            a16 = __hfma2(E3, q3h[i], a16);
            float2 f = __half22float2(a16);
            accf[2*i]   += f.x;
            accf[2*i+1] += f.y;
        }
        dacc += e0 + e1 + e2 + e3;
    };

    int j = beg;
    int nfull = (end - beg) >> 3;
    for (int it=0; it<nfull; ++it, j+=8) body(j, false);
    if (j < end) body(j, true);

    #pragma unroll
    for (int c=0;c<8;c++) accf[c] += __shfl_xor(accf[c], 32);
    dacc += __shfl_xor(dacc, 32);
    if (l < 32){
        float inv = 1.f / (dacc + 1e-16f);
        float4 B0 = *(const float4*)(b + l*8);
        float4 B1 = *(const float4*)(b + l*8 + 4);
        float4 st;
        __half2* sp = (__half2*)&st;
        sp[0] = __floats2half2_rn(elu1(fmaf(accf[0],inv,B0.x)), elu1(fmaf(accf[1],inv,B0.y)));
        sp[1] = __floats2half2_rn(elu1(fmaf(accf[2],inv,B0.z)), elu1(fmaf(accf[3],inv,B0.w)));
        sp[2] = __floats2half2_rn(elu1(fmaf(accf[4],inv,B1.x)), elu1(fmaf(accf[5],inv,B1.y)));
        sp[3] = __floats2half2_rn(elu1(fmaf(accf[6],inv,B1.z)), elu1(fmaf(accf[7],inv,B1.w)));
        *(float4*)(h1h + (size_t)n*256 + l*8) = st;
    }
}

// ---- fused GAT layer 2: wave per node; 8 lanes/edge x 8 ch;
// 8 slots x 2 unroll = 16 edges in flight. 32-bit gather offsets.
__global__ __launch_bounds__(256) void k_gat2(const __half* __restrict__ xlh,
        const __half* __restrict__ xrh, const int* __restrict__ srcs,
        const int* __restrict__ rowptr, const float* __restrict__ att,
        const float* __restrict__ b, float* __restrict__ h2){
    int w = threadIdx.x >> 6, l = threadIdx.x & 63;
    int n = blockIdx.x*4 + w;
    int g = l >> 3, sub = l & 7;
    const float4* xh4 = (const float4*)xlh;   // 8 f4 per row
    float4 rq = *(const float4*)(xrh + (size_t)n*64 + sub*8);
    __half2 r2[4];
    { const __half2* rh = (const __half2*)&rq;
      r2[0]=rh[0]; r2[1]=rh[1]; r2[2]=rh[2]; r2[3]=rh[3]; }
    float4 A0v = *(const float4*)(att + sub*8);
    float4 A1v = *(const float4*)(att + sub*8 + 4);
    const float C6 = 0.6f*L2E, C4 = 0.4f*L2E;
    __half2 A6[4] = { __floats2half2_rn(A0v.x*C6, A0v.y*C6),
                      __floats2half2_rn(A0v.z*C6, A0v.w*C6),
                      __floats2half2_rn(A1v.x*C6, A1v.y*C6),
                      __floats2half2_rn(A1v.z*C6, A1v.w*C6) };
    __half2 A4[4] = { __floats2half2_rn(A0v.x*C4, A0v.y*C4),
                      __floats2half2_rn(A0v.z*C4, A0v.w*C4),
                      __floats2half2_rn(A1v.x*C4, A1v.y*C4),
                      __floats2half2_rn(A1v.z*C4, A1v.w*C4) };
    const __half2 Z2 = __floats2half2_rn(0.f, 0.f);
    __half2 a16[4] = {Z2, Z2, Z2, Z2};
    float dacc = 0.f;
    int beg = rowptr[n], end = rowptr[n+1];

    auto body = [&](int j, bool checked){
        int j0 = j+g, j1 = j+8+g;
        bool c0=true, c1=true;
        if (checked){
            c0 = j0<end; c1 = j1<end;
            j0 = c0?j0:beg; j1 = c1?j1:beg;
        }
        int s0 = srcs[j0], s1 = srcs[j1];
        float4 q0 = xh4[(unsigned)(s0*8 + sub)];
        float4 q1 = xh4[(unsigned)(s1*8 + sub)];
        float p0 = pkdot(q0, r2, A6, A4);
        float p1 = pkdot(q1, r2, A6, A4);
        #pragma unroll
        for (int off=1; off<8; off<<=1){
            p0 += __shfl_xor(p0, off);
            p1 += __shfl_xor(p1, off);
        }
        float e0 = exp2f(p0), e1 = exp2f(p1);
        if (checked){ e0 = c0?e0:0.f; e1 = c1?e1:0.f; }
        __half2 E0 = bcast_h2(e0);
        __half2 E1 = bcast_h2(e1);
        const __half2* q0h = (const __half2*)&q0;
        const __half2* q1h = (const __half2*)&q1;
        #pragma unroll
        for (int i=0;i<4;i++){
            a16[i] = __hfma2(E0, q0h[i], a16[i]);
            a16[i] = __hfma2(E1, q1h[i], a16[i]);
        }
        dacc += e0 + e1;
    };

    int j = beg;
    int nfull = (end - beg) >> 4;
    for (int it=0; it<nfull; ++it, j+=16) body(j, false);
    if (j < end) body(j, true);

    float accf[8];
    #pragma unroll
    for (int i=0;i<4;i++){
        float2 f = __half22float2(a16[i]);
        accf[2*i] = f.x; accf[2*i+1] = f.y;
    }
    #pragma unroll
    for (int off=8; off<64; off<<=1){
        #pragma unroll
        for (int c=0;c<8;c++) accf[c] += __shfl_xor(accf[c], off);
        dacc += __shfl_xor(dacc, off);
    }
    if (l < 8){
        float inv = 1.f / (dacc + 1e-16f);
        float4 B0 = *(const float4*)(b + l*8);
        float4 B1 = *(const float4*)(b + l*8 + 4);
        float4 o0, o1;
        o0.x = elu1(fmaf(accf[0], inv, B0.x));
        o0.y = elu1(fmaf(accf[1], inv, B0.y));
        o0.z = elu1(fmaf(accf[2], inv, B0.z));
        o0.w = elu1(fmaf(accf[3], inv, B0.w));
        o1.x = elu1(fmaf(accf[4], inv, B1.x));
        o1.y = elu1(fmaf(accf[5], inv, B1.y));
        o1.z = elu1(fmaf(accf[6], inv, B1.z));
        o1.w = elu1(fmaf(accf[7], inv, B1.w));
        float4* op = (float4*)(h2 + (size_t)n*64 + l*8);
        op[0] = o0; op[1] = o1;
    }
}

__device__ __forceinline__ int lower_bound_i(const int* a, int n, int key){
    int lo = 0, hi = n;
    while (lo < hi){ int mid = (lo+hi)>>1; if (a[mid] < key) lo = mid+1; else hi = mid; }
    return lo;
}

// ---- mean pool: grid (64 graphs, 8 parts); block-reduced, 64 atomics/block
__global__ __launch_bounds__(256) void k_pool(const float* __restrict__ h2,
        const int* __restrict__ batch, float* __restrict__ pooled){
    int gph = blockIdx.x, part = blockIdx.y;
    int t = threadIdx.x, c = t & 63, q = t >> 6;
    int start = lower_bound_i(batch, N_NODES, gph);
    int end   = lower_bound_i(batch, N_NODES, gph+1);
    int len = end - start;
    int is = start + (int)(((long long)len*part) >> 3);
    int ie = start + (int)(((long long)len*(part+1)) >> 3);
    float s = 0.f;
    for (int i = is + q; i < ie; i += 4) s += h2[(size_t)i*64 + c];
    __shared__ float red[256];
    red[t] = s; __syncthreads();
    if (q == 0){
        float tot = red[c] + red[64+c] + red[128+c] + red[192+c];
        atomicAdd(&pooled[gph*64 + c], tot);
    }
}

// ---- MLP head (pooled sums -> mean -> 64 -> relu -> 2)
__global__ __launch_bounds__(64) void k_mlp(const float* __restrict__ pooled,
        const int* __restrict__ batch,
        const float* __restrict__ W3, const float* __restrict__ b3,
        const float* __restrict__ W4, const float* __restrict__ b4,
        float* __restrict__ out){
    int gph = blockIdx.x, t = threadIdx.x;
    __shared__ float ps[64], zs[64];
    int start = lower_bound_i(batch, N_NODES, gph);
    int end   = lower_bound_i(batch, N_NODES, gph+1);
    float cnt = fmaxf((float)(end - start), 1.f);
    ps[t] = pooled[gph*64 + t] / cnt;
    __syncthreads();
    float a = b3[t];
    for (int k=0;k<64;k++) a = fmaf(ps[k], W3[k*64+t], a);
    zs[t] = fmaxf(a, 0.f); __syncthreads();
    if (t < 2){
        float o = b4[t];
        for (int k=0;k<64;k++) o = fmaf(zs[k], W4[k*2+t], o);
        out[gph*2 + t] = o;
    }
}

extern "C" void kernel_launch(void* const* d_in, const int* in_sizes, int n_in,
                              void* d_out, int out_size, void* d_ws, size_t ws_size,
                              hipStream_t stream) {
    const float* x    = (const float*)d_in[0];
    const int*   ei   = (const int*)  d_in[1];   // [2, E] flat
    const int*   batch= (const int*)  d_in[2];
    const float* Wl1  = (const float*)d_in[3];
    const float* Wr1  = (const float*)d_in[4];
    const float* att1 = (const float*)d_in[5];
    const float* b1   = (const float*)d_in[6];
    const float* Wl2  = (const float*)d_in[7];
    const float* Wr2  = (const float*)d_in[8];
    const float* att2 = (const float*)d_in[9];
    const float* b2   = (const float*)d_in[10];
    const float* W3   = (const float*)d_in[11];
    const float* b3   = (const float*)d_in[12];
    const float* W4   = (const float*)d_in[13];
    const float* b4   = (const float*)d_in[14];
    float* out = (float*)d_out;

    // workspace layout
    char* wsp = (char*)d_ws;
    size_t off = 0;
    auto alloc = [&](size_t bytes) -> char* {
        char* p = wsp + off; off += (bytes + 255) & ~(size_t)255; return p;
    };
    __half* xh    = (__half*)alloc((size_t)N_NODES*64*2);     // 6.4 MB
    __half* Wt1   = (__half*)alloc(512*64*2);                 // [col][k]
    __half* Wt2   = (__half*)alloc(128*256*2);                // [col][k]
    __half* xl1h  = (__half*)alloc((size_t)N_NODES*256*2);    // 25.6 MB
    __half* xr1h  = (__half*)alloc((size_t)N_NODES*256*2);    // 25.6 MB
    __half* h1h   = (__half*)alloc((size_t)N_NODES*256*2);    // 25.6 MB
    int* rowptr   = (int*)alloc((N_NODES+1)*4);
    int* partial  = (int*)alloc(64*4);
    int* srcs     = (int*)alloc((size_t)N_EDGES*4);
    int* ranks    = (int*)alloc((size_t)N_EDGES*4);
    int* deg      = (int*)alloc(N_NODES*4);
    float* pooled = (float*)alloc(N_GRAPHS*64*4);
    // overlays (dead-region reuse after k_gat1)
    __half* xl2h  = xl1h;                                     // [N,64] fp16
    __half* xr2h  = xl1h + (size_t)N_NODES*64;                // [N,64] fp16
    float*  h2    = (float*)xr1h;                             // [N,64] f32

    hipMemsetAsync(deg, 0, (size_t)N_NODES*sizeof(int), stream);
    k_prep<<<782+3125+256, 256, 0, stream>>>(x, Wl1, Wr1, Wl2, Wr2, ei,
                                             xh, Wt1, Wt2, deg, ranks, pooled);
    k_scan_a<<<49, 1024, 0, stream>>>(deg, rowptr, partial);
    k_scan_c<<<49, 1024, 0, stream>>>(rowptr, partial);

    k_mm1<<<dim3(782,2), 256, 0, stream>>>(xh, Wt1, xl1h, xr1h,
                                           ei, ranks, rowptr, srcs);
    k_gat1<<<N_NODES/4, 256, 0, stream>>>(xl1h, xr1h, srcs, rowptr, att1, b1, h1h);
    k_mm2<<<782, 256, 0, stream>>>(h1h, Wt2, xl2h, xr2h);
    k_gat2<<<N_NODES/4, 256, 0, stream>>>(xl2h, xr2h, srcs, rowptr, att2, b2, h2);
    k_pool<<<dim3(N_GRAPHS,8), 256, 0, stream>>>(h2, batch, pooled);
    k_mlp<<<N_GRAPHS, 64, 0, stream>>>(pooled, batch, W3, b3, W4, b4, out);
}

// Round 14
// 259.429 us; speedup vs baseline: 1.0174x; 1.0174x over previous
//
#include <hip/hip_runtime.h>
#include <hip/hip_fp16.h>
#include <math.h>

#define N_NODES 50000
#define N_EDGES 800000
#define N_GRAPHS 64
#define L2E 1.44269504f
#define NPAD 50176                 // padded node stride for deg8/off8
#define NPART 8

#if __has_builtin(__builtin_amdgcn_fdot2)
#define HAS_FDOT2 1
typedef _Float16 h2_t __attribute__((ext_vector_type(2)));
#else
#define HAS_FDOT2 0
#endif

typedef _Float16 f16x8 __attribute__((ext_vector_type(8)));
typedef float f32x4 __attribute__((ext_vector_type(4)));

__device__ __forceinline__ float elu1(float v){ return v > 0.f ? v : expm1f(v); }

__device__ __forceinline__ __half2 bcast_h2(float e){
    return __builtin_bit_cast(__half2, __builtin_amdgcn_cvt_pkrtz(e, e));
}

// folded logit partial: sum over 8 ch of (A6*u + A4*|u|), u = q + r (fp16 pk).
__device__ __forceinline__ float pkdot(float4 q, const __half2* r2,
        const __half2* A6, const __half2* A4){
    const __half2* qh = (const __half2*)&q;
    float p = 0.f;
#if HAS_FDOT2
    #pragma unroll
    for (int i=0;i<4;i++){
        __half2 u = __hadd2(qh[i], r2[i]);
        __half2 ua = __builtin_bit_cast(__half2,
            __builtin_bit_cast(unsigned, u) & 0x7FFF7FFFu);
        p = __builtin_amdgcn_fdot2(__builtin_bit_cast(h2_t,u),
                                   __builtin_bit_cast(h2_t,A6[i]), p, false);
        p = __builtin_amdgcn_fdot2(__builtin_bit_cast(h2_t,ua),
                                   __builtin_bit_cast(h2_t,A4[i]), p, false);
    }
#else
    #pragma unroll
    for (int i=0;i<4;i++){
        float2 qf = __half22float2(qh[i]);
        float2 rf = __half22float2(r2[i]);
        float2 s6 = __half22float2(A6[i]);
        float2 s4 = __half22float2(A4[i]);
        float u0 = qf.x + rf.x, u1 = qf.y + rf.y;
        p = fmaf(s6.x, u0, fmaf(s4.x, fabsf(u0), p));
        p = fmaf(s6.y, u1, fmaf(s4.y, fabsf(u1), p));
    }
#endif
    return p;
}

// ---- prep: [0,782): 8-way-partitioned dst histogram + rank capture;
// [782,3907): x f32->fp16 ; [3907,4163): weight cvt+transpose (+ pooled zero).
// deg8 zeroed by memset. rank word = local_rank | part<<27.
__global__ __launch_bounds__(256) void k_prep(const float* __restrict__ x,
        const float* __restrict__ Wl1, const float* __restrict__ Wr1,
        const float* __restrict__ Wl2, const float* __restrict__ Wr2,
        const int* __restrict__ ei,
        __half* __restrict__ xh, __half* __restrict__ Wt1, __half* __restrict__ Wt2,
        int* __restrict__ deg8, int* __restrict__ ranks, float* __restrict__ pooled){
    int t = threadIdx.x, bk = blockIdx.x;
    if (bk < 782){
        int e4 = bk*256 + t;
        if (e4 < N_EDGES/4){
            int part = bk & (NPART-1);
            int* dp = deg8 + part*NPAD;
            int ptag = part << 27;
            int4 d = ((const int4*)(ei + N_EDGES))[e4];
            int4 r;
            r.x = atomicAdd(&dp[d.x],1) | ptag;
            r.y = atomicAdd(&dp[d.y],1) | ptag;
            r.z = atomicAdd(&dp[d.z],1) | ptag;
            r.w = atomicAdd(&dp[d.w],1) | ptag;
            ((int4*)ranks)[e4] = r;
        }
    } else if (bk < 3907){
        int idx = (bk-782)*256 + t;            // float4 index, 800000 total
        float4 v = ((const float4*)x)[idx];
        __half2* dst = (__half2*)xh + (size_t)idx*2;
        dst[0] = __floats2half2_rn(v.x, v.y);
        dst[1] = __floats2half2_rn(v.z, v.w);
    } else {
        int elem = (bk-3907)*256 + t;          // 0..65535
        if (elem < 32768){
            int c = elem >> 6, k = elem & 63;  // Wt1[c][k], c in [0,512)
            float v = (c < 256) ? Wl1[k*256 + c] : Wr1[k*256 + (c-256)];
            Wt1[elem] = __float2half(v);
        } else {
            int e2 = elem - 32768;
            int c = e2 >> 8, k = e2 & 255;     // Wt2[c][k], c in [0,128)
            float v = (c < 64) ? Wl2[k*64 + c] : Wr2[k*64 + (c-64)];
            Wt2[e2] = __float2half(v);
        }
        if (elem < N_GRAPHS*64) pooled[elem] = 0.f;
    }
}

// scan_a: per node, cross-part exclusive offsets (off8) + total degree;
// then block-level scan of totals.
__global__ __launch_bounds__(1024) void k_scan_a(const int* __restrict__ deg8,
        int* __restrict__ off8, int* __restrict__ rowptr, int* __restrict__ partial){
    __shared__ int s[1024];
    int t = threadIdx.x; int i = blockIdx.x*1024 + t;
    int v = 0;
    if (i < N_NODES){
        int run = 0;
        #pragma unroll
        for (int xp=0; xp<NPART; xp++){
            off8[xp*NPAD + i] = run;
            run += deg8[xp*NPAD + i];
        }
        v = run;
    }
    s[t] = v; __syncthreads();
    for (int off=1; off<1024; off<<=1){
        int add = (t>=off) ? s[t-off] : 0;
        __syncthreads();
        s[t] += add;
        __syncthreads();
    }
    if (i < N_NODES) rowptr[i] = s[t] - v;
    if (t == 1023) partial[blockIdx.x] = s[1023];
}

__global__ __launch_bounds__(1024) void k_scan_c(int* __restrict__ rowptr,
        const int* __restrict__ partial){
    __shared__ int base;
    if (threadIdx.x == 0){
        int run = 0;
        for (int bk=0; bk<(int)blockIdx.x; bk++) run += partial[bk];
        base = run;
    }
    __syncthreads();
    int i = blockIdx.x*1024 + threadIdx.x;
    if (i < N_NODES){
        rowptr[i] += base;
    } else if (i == N_NODES){
        rowptr[N_NODES] = N_EDGES;
    }
}

// ---- mm1 (+ atomic-free scatter on blockIdx.y==0):
// xh [N,64] fp16 @ Wt1^T -> xl1h|xr1h [N,256] fp16, MFMA 16x16x32.
__global__ __launch_bounds__(256) void k_mm1(const __half* __restrict__ xh,
        const __half* __restrict__ Wt1,
        __half* __restrict__ xl1h, __half* __restrict__ xr1h,
        const int* __restrict__ ei, const int* __restrict__ ranks,
        const int* __restrict__ rowptr, const int* __restrict__ off8,
        int* __restrict__ srcs){
    if (blockIdx.y == 0){
        int e4 = blockIdx.x*256 + threadIdx.x;
        if (e4 < N_EDGES/4){
            int4 sv = ((const int4*)ei)[e4];
            int4 dv = ((const int4*)(ei + N_EDGES))[e4];
            int4 rv = ((const int4*)ranks)[e4];
            int p0 = (unsigned)rv.x >> 27, r0 = rv.x & 0x07FFFFFF;
            int p1 = (unsigned)rv.y >> 27, r1 = rv.y & 0x07FFFFFF;
            int p2 = (unsigned)rv.z >> 27, r2 = rv.z & 0x07FFFFFF;
            int p3 = (unsigned)rv.w >> 27, r3 = rv.w & 0x07FFFFFF;
            __builtin_nontemporal_store(sv.x, &srcs[rowptr[dv.x] + off8[p0*NPAD + dv.x] + r0]);
            __builtin_nontemporal_store(sv.y, &srcs[rowptr[dv.y] + off8[p1*NPAD + dv.y] + r1]);
            __builtin_nontemporal_store(sv.z, &srcs[rowptr[dv.z] + off8[p2*NPAD + dv.z] + r2]);
            __builtin_nontemporal_store(sv.w, &srcs[rowptr[dv.w] + off8[p3*NPAD + dv.w] + r3]);
        }
        return;
    }
    __shared__ __half lds[4][16*136];
    int w = threadIdx.x >> 6, l = threadIdx.x & 63;
    int r0 = blockIdx.x*64 + w*16;
    int lr = l & 15, lk = l >> 4, lk4 = lk*4;
    int ar = r0 + lr; if (ar >= N_NODES) ar = N_NODES-1;
    const __half* arow = xh + (size_t)ar*64;
    f16x8 a0 = *(const f16x8*)(arow + lk*8);
    f16x8 a1 = *(const f16x8*)(arow + 32 + lk*8);
    #pragma unroll
    for (int cg=0; cg<4; cg++){
        f32x4 acc[8];
        #pragma unroll
        for (int ct=0; ct<8; ct++) acc[ct] = (f32x4){0.f,0.f,0.f,0.f};
        #pragma unroll
        for (int ct=0; ct<8; ct++){
            int col = cg*128 + ct*16 + lr;
            const __half* brow = Wt1 + (size_t)col*64;
            f16x8 b0 = *(const f16x8*)(brow + lk*8);
            f16x8 b1 = *(const f16x8*)(brow + 32 + lk*8);
            acc[ct] = __builtin_amdgcn_mfma_f32_16x16x32_f16(a0, b0, acc[ct], 0,0,0);
            acc[ct] = __builtin_amdgcn_mfma_f32_16x16x32_f16(a1, b1, acc[ct], 0,0,0);
        }
        #pragma unroll
        for (int ct=0; ct<8; ct++){
            #pragma unroll
            for (int i=0;i<4;i++)
                lds[w][(lk4+i)*136 + ct*16 + lr] = __float2half(acc[ct][i]);
        }
        __half* base = (cg < 2) ? xl1h : xr1h;
        int cbase = (cg & 1)*128;
        #pragma unroll
        for (int rr=0; rr<4; rr++){
            int row = rr*4 + lk;
            float4 v = *(const float4*)&lds[w][row*136 + lr*8];
            int grow = r0 + row;
            if (grow < N_NODES)
                *(float4*)&base[(size_t)grow*256 + cbase + lr*8] = v;
        }
    }
}

// ---- mm2: h1h [N,256] fp16 @ Wt2^T -> xl2h|xr2h [N,64] fp16
__global__ __launch_bounds__(256) void k_mm2(const __half* __restrict__ h1h,
        const __half* __restrict__ Wt2,
        __half* __restrict__ xl2h, __half* __restrict__ xr2h){
    __shared__ __half lds[4][16*72];
    int w = threadIdx.x >> 6, l = threadIdx.x & 63;
    int r0 = blockIdx.x*64 + w*16;
    int lr = l & 15, lk = l >> 4, lk4 = lk*4;
    int ar = r0 + lr; if (ar >= N_NODES) ar = N_NODES-1;
    const __half* arow = h1h + (size_t)ar*256;
    f16x8 a[8];
    #pragma unroll
    for (int ks=0; ks<8; ks++) a[ks] = *(const f16x8*)(arow + ks*32 + lk*8);
    #pragma unroll
    for (int cg=0; cg<2; cg++){
        f32x4 acc[4];
        #pragma unroll
        for (int ct=0; ct<4; ct++) acc[ct] = (f32x4){0.f,0.f,0.f,0.f};
        #pragma unroll
        for (int ks=0; ks<8; ks++){
            #pragma unroll
            for (int ct=0; ct<4; ct++){
                int col = cg*64 + ct*16 + lr;
                f16x8 bf = *(const f16x8*)(Wt2 + (size_t)col*256 + ks*32 + lk*8);
                acc[ct] = __builtin_amdgcn_mfma_f32_16x16x32_f16(a[ks], bf, acc[ct], 0,0,0);
            }
        }
        #pragma unroll
        for (int ct=0; ct<4; ct++){
            #pragma unroll
            for (int i=0;i<4;i++)
                lds[w][(lk4+i)*72 + ct*16 + lr] = __float2half(acc[ct][i]);
        }
        __half* base = (cg == 0) ? xl2h : xr2h;
        #pragma unroll
        for (int rr=0; rr<2; rr++){
            int row = rr*8 + (l>>3);
            float4 v = *(const float4*)&lds[w][row*72 + (l&7)*8];
            int grow = r0 + row;
            if (grow < N_NODES)
                *(float4*)&base[(size_t)grow*64 + (l&7)*8] = v;
        }
    }
}

// ---- fused GAT layer 1: wave per node, 4/block. 32 lanes/edge x 8 ch;
// 4 edges in flight. 32-bit gather offsets.
__global__ __launch_bounds__(256) void k_gat1(const __half* __restrict__ xlh,
        const __half* __restrict__ xrh, const int* __restrict__ srcs,
        const int* __restrict__ rowptr, const float* __restrict__ att,
        const float* __restrict__ b, __half* __restrict__ h1h){
    int w = threadIdx.x >> 6, l = threadIdx.x & 63;
    int n = blockIdx.x*4 + w;
    int g = l >> 5, sub = l & 31;
    const float4* xh4 = (const float4*)xlh;   // 32 f4 per row
    float4 rq = *(const float4*)(xrh + (size_t)n*256 + sub*8);
    __half2 r2[4];
    { const __half2* rh = (const __half2*)&rq;
      r2[0]=rh[0]; r2[1]=rh[1]; r2[2]=rh[2]; r2[3]=rh[3]; }
    float4 A0v = *(const float4*)(att + sub*8);
    float4 A1v = *(const float4*)(att + sub*8 + 4);
    const float C6 = 0.6f*L2E, C4 = 0.4f*L2E;
    __half2 A6[4] = { __floats2half2_rn(A0v.x*C6, A0v.y*C6),
                      __floats2half2_rn(A0v.z*C6, A0v.w*C6),
                      __floats2half2_rn(A1v.x*C6, A1v.y*C6),
                      __floats2half2_rn(A1v.z*C6, A1v.w*C6) };
    __half2 A4[4] = { __floats2half2_rn(A0v.x*C4, A0v.y*C4),
                      __floats2half2_rn(A0v.z*C4, A0v.w*C4),
                      __floats2half2_rn(A1v.x*C4, A1v.y*C4),
                      __floats2half2_rn(A1v.z*C4, A1v.w*C4) };
    const __half2 Z2 = __floats2half2_rn(0.f, 0.f);
    float accf[8];
    #pragma unroll
    for (int c=0;c<8;c++) accf[c]=0.f;
    float dacc = 0.f;
    int beg = rowptr[n], end = rowptr[n+1];

    auto body = [&](int j, bool checked){
        int j0=j+g, j1=j+2+g, j2=j+4+g, j3=j+6+g;
        bool c0=true, c1=true, c2=true, c3=true;
        if (checked){
            c0 = j0<end; c1 = j1<end; c2 = j2<end; c3 = j3<end;
            j0 = c0?j0:beg; j1 = c1?j1:beg; j2 = c2?j2:beg; j3 = c3?j3:beg;
        }
        int s0 = srcs[j0], s1 = srcs[j1], s2 = srcs[j2], s3 = srcs[j3];
        float4 q0 = xh4[(unsigned)(s0*32 + sub)];
        float4 q1 = xh4[(unsigned)(s1*32 + sub)];
        float4 q2 = xh4[(unsigned)(s2*32 + sub)];
        float4 q3 = xh4[(unsigned)(s3*32 + sub)];
        float p0 = pkdot(q0, r2, A6, A4);
        float p1 = pkdot(q1, r2, A6, A4);
        float p2 = pkdot(q2, r2, A6, A4);
        float p3 = pkdot(q3, r2, A6, A4);
        #pragma unroll
        for (int off=1; off<8; off<<=1){
            p0 += __shfl_xor(p0, off);
            p1 += __shfl_xor(p1, off);
            p2 += __shfl_xor(p2, off);
            p3 += __shfl_xor(p3, off);
        }
        float e0 = exp2f(p0), e1 = exp2f(p1), e2 = exp2f(p2), e3 = exp2f(p3);
        if (checked){
            e0 = c0?e0:0.f; e1 = c1?e1:0.f; e2 = c2?e2:0.f; e3 = c3?e3:0.f;
        }
        __half2 E0 = bcast_h2(e0);
        __half2 E1 = bcast_h2(e1);
        __half2 E2 = bcast_h2(e2);
        __half2 E3 = bcast_h2(e3);
        const __half2* q0h = (const __half2*)&q0;
        const __half2* q1h = (const __half2*)&q1;
        const __half2* q2h = (const __half2*)&q2;
        const __half2* q3h = (const __half2*)&q3;
        #pragma unroll
        for (int i=0;i<4;i++){
            __half2 a16 = __hfma2(E0, q0h[i], Z2);
            a16 = __hfma2(E1, q1h[i], a16);
            a16 = __hfma2(E2, q2h[i], a16);
            a16 = __hfma2(E3, q3h[i], a16);
            float2 f = __half22float2(a16);
            accf[2*i]   += f.x;
            accf[2*i+1] += f.y;
        }
        dacc += e0 + e1 + e2 + e3;
    };

    int j = beg;
    int nfull = (end - beg) >> 3;
    for (int it=0; it<nfull; ++it, j+=8) body(j, false);
    if (j < end) body(j, true);

    #pragma unroll
    for (int c=0;c<8;c++) accf[c] += __shfl_xor(accf[c], 32);
    dacc += __shfl_xor(dacc, 32);
    if (l < 32){
        float inv = 1.f / (dacc + 1e-16f);
        float4 B0 = *(const float4*)(b + l*8);
        float4 B1 = *(const float4*)(b + l*8 + 4);
        float4 st;
        __half2* sp = (__half2*)&st;
        sp[0] = __floats2half2_rn(elu1(fmaf(accf[0],inv,B0.x)), elu1(fmaf(accf[1],inv,B0.y)));
        sp[1] = __floats2half2_rn(elu1(fmaf(accf[2],inv,B0.z)), elu1(fmaf(accf[3],inv,B0.w)));
        sp[2] = __floats2half2_rn(elu1(fmaf(accf[4],inv,B1.x)), elu1(fmaf(accf[5],inv,B1.y)));
        sp[3] = __floats2half2_rn(elu1(fmaf(accf[6],inv,B1.z)), elu1(fmaf(accf[7],inv,B1.w)));
        *(float4*)(h1h + (size_t)n*256 + l*8) = st;
    }
}

// ---- fused GAT layer 2: wave per node; 8 lanes/edge x 8 ch; 16 edges in
// flight. h2 out fp16 (pool averages the rounding noise away).
__global__ __launch_bounds__(256) void k_gat2(const __half* __restrict__ xlh,
        const __half* __restrict__ xrh, const int* __restrict__ srcs,
        const int* __restrict__ rowptr, const float* __restrict__ att,
        const float* __restrict__ b, __half* __restrict__ h2h){
    int w = threadIdx.x >> 6, l = threadIdx.x & 63;
    int n = blockIdx.x*4 + w;
    int g = l >> 3, sub = l & 7;
    const float4* xh4 = (const float4*)xlh;   // 8 f4 per row
    float4 rq = *(const float4*)(xrh + (size_t)n*64 + sub*8);
    __half2 r2[4];
    { const __half2* rh = (const __half2*)&rq;
      r2[0]=rh[0]; r2[1]=rh[1]; r2[2]=rh[2]; r2[3]=rh[3]; }
    float4 A0v = *(const float4*)(att + sub*8);
    float4 A1v = *(const float4*)(att + sub*8 + 4);
    const float C6 = 0.6f*L2E, C4 = 0.4f*L2E;
    __half2 A6[4] = { __floats2half2_rn(A0v.x*C6, A0v.y*C6),
                      __floats2half2_rn(A0v.z*C6, A0v.w*C6),
                      __floats2half2_rn(A1v.x*C6, A1v.y*C6),
                      __floats2half2_rn(A1v.z*C6, A1v.w*C6) };
    __half2 A4[4] = { __floats2half2_rn(A0v.x*C4, A0v.y*C4),
                      __floats2half2_rn(A0v.z*C4, A0v.w*C4),
                      __floats2half2_rn(A1v.x*C4, A1v.y*C4),
                      __floats2half2_rn(A1v.z*C4, A1v.w*C4) };
    const __half2 Z2 = __floats2half2_rn(0.f, 0.f);
    __half2 a16[4] = {Z2, Z2, Z2, Z2};
    float dacc = 0.f;
    int beg = rowptr[n], end = rowptr[n+1];

    auto body = [&](int j, bool checked){
        int j0 = j+g, j1 = j+8+g;
        bool c0=true, c1=true;
        if (checked){
            c0 = j0<end; c1 = j1<end;
            j0 = c0?j0:beg; j1 = c1?j1:beg;
        }
        int s0 = srcs[j0], s1 = srcs[j1];
        float4 q0 = xh4[(unsigned)(s0*8 + sub)];
        float4 q1 = xh4[(unsigned)(s1*8 + sub)];
        float p0 = pkdot(q0, r2, A6, A4);
        float p1 = pkdot(q1, r2, A6, A4);
        #pragma unroll
        for (int off=1; off<8; off<<=1){
            p0 += __shfl_xor(p0, off);
            p1 += __shfl_xor(p1, off);
        }
        float e0 = exp2f(p0), e1 = exp2f(p1);
        if (checked){ e0 = c0?e0:0.f; e1 = c1?e1:0.f; }
        __half2 E0 = bcast_h2(e0);
        __half2 E1 = bcast_h2(e1);
        const __half2* q0h = (const __half2*)&q0;
        const __half2* q1h = (const __half2*)&q1;
        #pragma unroll
        for (int i=0;i<4;i++){
            a16[i] = __hfma2(E0, q0h[i], a16[i]);
            a16[i] = __hfma2(E1, q1h[i], a16[i]);
        }
        dacc += e0 + e1;
    };

    int j = beg;
    int nfull = (end - beg) >> 4;
    for (int it=0; it<nfull; ++it, j+=16) body(j, false);
    if (j < end) body(j, true);

    float accf[8];
    #pragma unroll
    for (int i=0;i<4;i++){
        float2 f = __half22float2(a16[i]);
        accf[2*i] = f.x; accf[2*i+1] = f.y;
    }
    #pragma unroll
    for (int off=8; off<64; off<<=1){
        #pragma unroll
        for (int c=0;c<8;c++) accf[c] += __shfl_xor(accf[c], off);
        dacc += __shfl_xor(dacc, off);
    }
    if (l < 8){
        float inv = 1.f / (dacc + 1e-16f);
        float4 B0 = *(const float4*)(b + l*8);
        float4 B1 = *(const float4*)(b + l*8 + 4);
        float4 st;
        __half2* sp = (__half2*)&st;
        sp[0] = __floats2half2_rn(elu1(fmaf(accf[0],inv,B0.x)), elu1(fmaf(accf[1],inv,B0.y)));
        sp[1] = __floats2half2_rn(elu1(fmaf(accf[2],inv,B0.z)), elu1(fmaf(accf[3],inv,B0.w)));
        sp[2] = __floats2half2_rn(elu1(fmaf(accf[4],inv,B1.x)), elu1(fmaf(accf[5],inv,B1.y)));
        sp[3] = __floats2half2_rn(elu1(fmaf(accf[6],inv,B1.z)), elu1(fmaf(accf[7],inv,B1.w)));
        *(float4*)(h2h + (size_t)n*64 + l*8) = st;
    }
}

__device__ __forceinline__ int lower_bound_i(const int* a, int n, int key){
    int lo = 0, hi = n;
    while (lo < hi){ int mid = (lo+hi)>>1; if (a[mid] < key) lo = mid+1; else hi = mid; }
    return lo;
}

// ---- mean pool over fp16 h2: grid (64 graphs, 8 parts); lane = channel-pair
__global__ __launch_bounds__(256) void k_pool(const __half* __restrict__ h2h,
        const int* __restrict__ batch, float* __restrict__ pooled){
    int gph = blockIdx.x, part = blockIdx.y;
    int t = threadIdx.x, c2 = t & 31, q = t >> 5;     // 32 ch-pairs x 8 rows
    int start = lower_bound_i(batch, N_NODES, gph);
    int end   = lower_bound_i(batch, N_NODES, gph+1);
    int len = end - start;
    int is = start + (int)(((long long)len*part) >> 3);
    int ie = start + (int)(((long long)len*(part+1)) >> 3);
    float2 s = make_float2(0.f, 0.f);
    const __half2* h22 = (const __half2*)h2h;
    for (int i = is + q; i < ie; i += 8){
        float2 f = __half22float2(h22[(unsigned)(i*32 + c2)]);
        s.x += f.x; s.y += f.y;
    }
    __shared__ float2 red[256];
    red[t] = s; __syncthreads();
    if (q == 0){
        float2 tot = red[c2];
        #pragma unroll
        for (int qq=1; qq<8; qq++){
            tot.x += red[qq*32 + c2].x;
            tot.y += red[qq*32 + c2].y;
        }
        atomicAdd(&pooled[gph*64 + c2*2],     tot.x);
        atomicAdd(&pooled[gph*64 + c2*2 + 1], tot.y);
    }
}

// ---- MLP head (pooled sums -> mean -> 64 -> relu -> 2)
__global__ __launch_bounds__(64) void k_mlp(const float* __restrict__ pooled,
        const int* __restrict__ batch,
        const float* __restrict__ W3, const float* __restrict__ b3,
        const float* __restrict__ W4, const float* __restrict__ b4,
        float* __restrict__ out){
    int gph = blockIdx.x, t = threadIdx.x;
    __shared__ float ps[64], zs[64];
    int start = lower_bound_i(batch, N_NODES, gph);
    int end   = lower_bound_i(batch, N_NODES, gph+1);
    float cnt = fmaxf((float)(end - start), 1.f);
    ps[t] = pooled[gph*64 + t] / cnt;
    __syncthreads();
    float a = b3[t];
    for (int k=0;k<64;k++) a = fmaf(ps[k], W3[k*64+t], a);
    zs[t] = fmaxf(a, 0.f); __syncthreads();
    if (t < 2){
        float o = b4[t];
        for (int k=0;k<64;k++) o = fmaf(zs[k], W4[k*2+t], o);
        out[gph*2 + t] = o;
    }
}

extern "C" void kernel_launch(void* const* d_in, const int* in_sizes, int n_in,
                              void* d_out, int out_size, void* d_ws, size_t ws_size,
                              hipStream_t stream) {
    const float* x    = (const float*)d_in[0];
    const int*   ei   = (const int*)  d_in[1];   // [2, E] flat
    const int*   batch= (const int*)  d_in[2];
    const float* Wl1  = (const float*)d_in[3];
    const float* Wr1  = (const float*)d_in[4];
    const float* att1 = (const float*)d_in[5];
    const float* b1   = (const float*)d_in[6];
    const float* Wl2  = (const float*)d_in[7];
    const float* Wr2  = (const float*)d_in[8];
    const float* att2 = (const float*)d_in[9];
    const float* b2   = (const float*)d_in[10];
    const float* W3   = (const float*)d_in[11];
    const float* b3   = (const float*)d_in[12];
    const float* W4   = (const float*)d_in[13];
    const float* b4   = (const float*)d_in[14];
    float* out = (float*)d_out;

    // workspace layout
    char* wsp = (char*)d_ws;
    size_t off = 0;
    auto alloc = [&](size_t bytes) -> char* {
        char* p = wsp + off; off += (bytes + 255) & ~(size_t)255; return p;
    };
    __half* xh    = (__half*)alloc((size_t)N_NODES*64*2);     // 6.4 MB
    __half* Wt1   = (__half*)alloc(512*64*2);                 // [col][k]
    __half* Wt2   = (__half*)alloc(128*256*2);                // [col][k]
    __half* xl1h  = (__half*)alloc((size_t)N_NODES*256*2);    // 25.6 MB
    __half* xr1h  = (__half*)alloc((size_t)N_NODES*256*2);    // 25.6 MB
    __half* h1h   = (__half*)alloc((size_t)N_NODES*256*2);    // 25.6 MB
    int* rowptr   = (int*)alloc((N_NODES+1)*4);
    int* partial  = (int*)alloc(64*4);
    int* srcs     = (int*)alloc((size_t)N_EDGES*4);
    int* ranks    = (int*)alloc((size_t)N_EDGES*4);
    int* deg8     = (int*)alloc((size_t)NPART*NPAD*4);        // 1.6 MB
    int* off8     = (int*)alloc((size_t)NPART*NPAD*4);        // 1.6 MB
    float* pooled = (float*)alloc(N_GRAPHS*64*4);
    // overlays (dead-region reuse after k_gat1)
    __half* xl2h  = xl1h;                                     // [N,64] fp16
    __half* xr2h  = xl1h + (size_t)N_NODES*64;                // [N,64] fp16
    __half* h2h   = (__half*)xr1h;                            // [N,64] fp16

    hipMemsetAsync(deg8, 0, (size_t)NPART*NPAD*sizeof(int), stream);
    k_prep<<<782+3125+256, 256, 0, stream>>>(x, Wl1, Wr1, Wl2, Wr2, ei,
                                             xh, Wt1, Wt2, deg8, ranks, pooled);
    k_scan_a<<<49, 1024, 0, stream>>>(deg8, off8, rowptr, partial);
    k_scan_c<<<49, 1024, 0, stream>>>(rowptr, partial);

    k_mm1<<<dim3(782,2), 256, 0, stream>>>(xh, Wt1, xl1h, xr1h,
                                           ei, ranks, rowptr, off8, srcs);
    k_gat1<<<N_NODES/4, 256, 0, stream>>>(xl1h, xr1h, srcs, rowptr, att1, b1, h1h);
    k_mm2<<<782, 256, 0, stream>>>(h1h, Wt2, xl2h, xr2h);
    k_gat2<<<N_NODES/4, 256, 0, stream>>>(xl2h, xr2h, srcs, rowptr, att2, b2, h2h);
    k_pool<<<dim3(N_GRAPHS,8), 256, 0, stream>>>(h2h, batch, pooled);
    k_mlp<<<N_GRAPHS, 64, 0, stream>>>(pooled, batch, W3, b3, W4, b4, out);
}

// Round 15
// 246.368 us; speedup vs baseline: 1.0713x; 1.0530x over previous
//
#include <hip/hip_runtime.h>
#include <hip/hip_fp16.h>
#include <math.h>

#define N_NODES 50000
#define N_EDGES 800000
#define N_GRAPHS 64
#define L2E 1.44269504f
#define NPAD 50176                 // padded node stride for deg8/off8
#define NPART 8

#if __has_builtin(__builtin_amdgcn_fdot2)
#define HAS_FDOT2 1
typedef _Float16 h2_t __attribute__((ext_vector_type(2)));
#else
#define HAS_FDOT2 0
#endif

typedef _Float16 f16x8 __attribute__((ext_vector_type(8)));
typedef float f32x4 __attribute__((ext_vector_type(4)));

__device__ __forceinline__ float elu1(float v){ return v > 0.f ? v : expm1f(v); }

__device__ __forceinline__ __half2 bcast_h2(float e){
    return __builtin_bit_cast(__half2, __builtin_amdgcn_cvt_pkrtz(e, e));
}

// folded logit partial: sum over 8 ch of (A6*u + A4*|u|), u = q + r (fp16 pk).
__device__ __forceinline__ float pkdot(float4 q, const __half2* r2,
        const __half2* A6, const __half2* A4){
    const __half2* qh = (const __half2*)&q;
    float p = 0.f;
#if HAS_FDOT2
    #pragma unroll
    for (int i=0;i<4;i++){
        __half2 u = __hadd2(qh[i], r2[i]);
        __half2 ua = __builtin_bit_cast(__half2,
            __builtin_bit_cast(unsigned, u) & 0x7FFF7FFFu);
        p = __builtin_amdgcn_fdot2(__builtin_bit_cast(h2_t,u),
                                   __builtin_bit_cast(h2_t,A6[i]), p, false);
        p = __builtin_amdgcn_fdot2(__builtin_bit_cast(h2_t,ua),
                                   __builtin_bit_cast(h2_t,A4[i]), p, false);
    }
#else
    #pragma unroll
    for (int i=0;i<4;i++){
        float2 qf = __half22float2(qh[i]);
        float2 rf = __half22float2(r2[i]);
        float2 s6 = __half22float2(A6[i]);
        float2 s4 = __half22float2(A4[i]);
        float u0 = qf.x + rf.x, u1 = qf.y + rf.y;
        p = fmaf(s6.x, u0, fmaf(s4.x, fabsf(u0), p));
        p = fmaf(s6.y, u1, fmaf(s4.y, fabsf(u1), p));
    }
#endif
    return p;
}

// ---- prep: [0,782): 8-way-partitioned dst histogram + rank capture;
// [782,3907): x f32->fp16 ; [3907,4163): weight cvt+transpose (+ pooled zero).
__global__ __launch_bounds__(256) void k_prep(const float* __restrict__ x,
        const float* __restrict__ Wl1, const float* __restrict__ Wr1,
        const float* __restrict__ Wl2, const float* __restrict__ Wr2,
        const int* __restrict__ ei,
        __half* __restrict__ xh, __half* __restrict__ Wt1, __half* __restrict__ Wt2,
        int* __restrict__ deg8, int* __restrict__ ranks, float* __restrict__ pooled){
    int t = threadIdx.x, bk = blockIdx.x;
    if (bk < 782){
        int e4 = bk*256 + t;
        if (e4 < N_EDGES/4){
            int part = bk & (NPART-1);
            int* dp = deg8 + part*NPAD;
            int ptag = part << 27;
            int4 d = ((const int4*)(ei + N_EDGES))[e4];
            int4 r;
            r.x = atomicAdd(&dp[d.x],1) | ptag;
            r.y = atomicAdd(&dp[d.y],1) | ptag;
            r.z = atomicAdd(&dp[d.z],1) | ptag;
            r.w = atomicAdd(&dp[d.w],1) | ptag;
            ((int4*)ranks)[e4] = r;
        }
    } else if (bk < 3907){
        int idx = (bk-782)*256 + t;            // float4 index, 800000 total
        float4 v = ((const float4*)x)[idx];
        __half2* dst = (__half2*)xh + (size_t)idx*2;
        dst[0] = __floats2half2_rn(v.x, v.y);
        dst[1] = __floats2half2_rn(v.z, v.w);
    } else {
        int elem = (bk-3907)*256 + t;          // 0..65535
        if (elem < 32768){
            int c = elem >> 6, k = elem & 63;  // Wt1[c][k], c in [0,512)
            float v = (c < 256) ? Wl1[k*256 + c] : Wr1[k*256 + (c-256)];
            Wt1[elem] = __float2half(v);
        } else {
            int e2 = elem - 32768;
            int c = e2 >> 8, k = e2 & 255;     // Wt2[c][k], c in [0,128)
            float v = (c < 64) ? Wl2[k*64 + c] : Wr2[k*64 + (c-64)];
            Wt2[e2] = __float2half(v);
        }
        if (elem < N_GRAPHS*64) pooled[elem] = 0.f;
    }
}

// scan_a: per node, cross-part exclusive offsets (off8) + total degree;
// then block-level scan of totals.
__global__ __launch_bounds__(1024) void k_scan_a(const int* __restrict__ deg8,
        int* __restrict__ off8, int* __restrict__ rowptr, int* __restrict__ partial){
    __shared__ int s[1024];
    int t = threadIdx.x; int i = blockIdx.x*1024 + t;
    int v = 0;
    if (i < N_NODES){
        int run = 0;
        #pragma unroll
        for (int xp=0; xp<NPART; xp++){
            off8[xp*NPAD + i] = run;
            run += deg8[xp*NPAD + i];
        }
        v = run;
    }
    s[t] = v; __syncthreads();
    for (int off=1; off<1024; off<<=1){
        int add = (t>=off) ? s[t-off] : 0;
        __syncthreads();
        s[t] += add;
        __syncthreads();
    }
    if (i < N_NODES) rowptr[i] = s[t] - v;
    if (t == 1023) partial[blockIdx.x] = s[1023];
}

__global__ __launch_bounds__(1024) void k_scan_c(int* __restrict__ rowptr,
        const int* __restrict__ partial){
    __shared__ int base;
    if (threadIdx.x == 0){
        int run = 0;
        for (int bk=0; bk<(int)blockIdx.x; bk++) run += partial[bk];
        base = run;
    }
    __syncthreads();
    int i = blockIdx.x*1024 + threadIdx.x;
    if (i < N_NODES){
        rowptr[i] += base;
    } else if (i == N_NODES){
        rowptr[N_NODES] = N_EDGES;
    }
}

// ---- mm1 (+ atomic-free scatter on blockIdx.y==0; PLAIN stores so the
// owning L2 can coalesce CSR-contiguous 4B writes into full sectors):
// xh [N,64] fp16 @ Wt1^T -> xl1h|xr1h [N,256] fp16, MFMA 16x16x32.
__global__ __launch_bounds__(256) void k_mm1(const __half* __restrict__ xh,
        const __half* __restrict__ Wt1,
        __half* __restrict__ xl1h, __half* __restrict__ xr1h,
        const int* __restrict__ ei, const int* __restrict__ ranks,
        const int* __restrict__ rowptr, const int* __restrict__ off8,
        int* __restrict__ srcs){
    if (blockIdx.y == 0){
        int e4 = blockIdx.x*256 + threadIdx.x;
        if (e4 < N_EDGES/4){
            int4 sv = ((const int4*)ei)[e4];
            int4 dv = ((const int4*)(ei + N_EDGES))[e4];
            int4 rv = ((const int4*)ranks)[e4];
            int p0 = (unsigned)rv.x >> 27, r0 = rv.x & 0x07FFFFFF;
            int p1 = (unsigned)rv.y >> 27, r1 = rv.y & 0x07FFFFFF;
            int p2 = (unsigned)rv.z >> 27, r2 = rv.z & 0x07FFFFFF;
            int p3 = (unsigned)rv.w >> 27, r3 = rv.w & 0x07FFFFFF;
            srcs[rowptr[dv.x] + off8[p0*NPAD + dv.x] + r0] = sv.x;
            srcs[rowptr[dv.y] + off8[p1*NPAD + dv.y] + r1] = sv.y;
            srcs[rowptr[dv.z] + off8[p2*NPAD + dv.z] + r2] = sv.z;
            srcs[rowptr[dv.w] + off8[p3*NPAD + dv.w] + r3] = sv.w;
        }
        return;
    }
    __shared__ __half lds[4][16*136];
    int w = threadIdx.x >> 6, l = threadIdx.x & 63;
    int r0 = blockIdx.x*64 + w*16;
    int lr = l & 15, lk = l >> 4, lk4 = lk*4;
    int ar = r0 + lr; if (ar >= N_NODES) ar = N_NODES-1;
    const __half* arow = xh + (size_t)ar*64;
    f16x8 a0 = *(const f16x8*)(arow + lk*8);
    f16x8 a1 = *(const f16x8*)(arow + 32 + lk*8);
    #pragma unroll
    for (int cg=0; cg<4; cg++){
        f32x4 acc[8];
        #pragma unroll
        for (int ct=0; ct<8; ct++) acc[ct] = (f32x4){0.f,0.f,0.f,0.f};
        #pragma unroll
        for (int ct=0; ct<8; ct++){
            int col = cg*128 + ct*16 + lr;
            const __half* brow = Wt1 + (size_t)col*64;
            f16x8 b0 = *(const f16x8*)(brow + lk*8);
            f16x8 b1 = *(const f16x8*)(brow + 32 + lk*8);
            acc[ct] = __builtin_amdgcn_mfma_f32_16x16x32_f16(a0, b0, acc[ct], 0,0,0);
            acc[ct] = __builtin_amdgcn_mfma_f32_16x16x32_f16(a1, b1, acc[ct], 0,0,0);
        }
        #pragma unroll
        for (int ct=0; ct<8; ct++){
            #pragma unroll
            for (int i=0;i<4;i++)
                lds[w][(lk4+i)*136 + ct*16 + lr] = __float2half(acc[ct][i]);
        }
        __half* base = (cg < 2) ? xl1h : xr1h;
        int cbase = (cg & 1)*128;
        #pragma unroll
        for (int rr=0; rr<4; rr++){
            int row = rr*4 + lk;
            float4 v = *(const float4*)&lds[w][row*136 + lr*8];
            int grow = r0 + row;
            if (grow < N_NODES)
                *(float4*)&base[(size_t)grow*256 + cbase + lr*8] = v;
        }
    }
}

// ---- mm2: h1h [N,256] fp16 @ Wt2^T -> xl2h|xr2h [N,64] fp16
__global__ __launch_bounds__(256) void k_mm2(const __half* __restrict__ h1h,
        const __half* __restrict__ Wt2,
        __half* __restrict__ xl2h, __half* __restrict__ xr2h){
    __shared__ __half lds[4][16*72];
    int w = threadIdx.x >> 6, l = threadIdx.x & 63;
    int r0 = blockIdx.x*64 + w*16;
    int lr = l & 15, lk = l >> 4, lk4 = lk*4;
    int ar = r0 + lr; if (ar >= N_NODES) ar = N_NODES-1;
    const __half* arow = h1h + (size_t)ar*256;
    f16x8 a[8];
    #pragma unroll
    for (int ks=0; ks<8; ks++) a[ks] = *(const f16x8*)(arow + ks*32 + lk*8);
    #pragma unroll
    for (int cg=0; cg<2; cg++){
        f32x4 acc[4];
        #pragma unroll
        for (int ct=0; ct<4; ct++) acc[ct] = (f32x4){0.f,0.f,0.f,0.f};
        #pragma unroll
        for (int ks=0; ks<8; ks++){
            #pragma unroll
            for (int ct=0; ct<4; ct++){
                int col = cg*64 + ct*16 + lr;
                f16x8 bf = *(const f16x8*)(Wt2 + (size_t)col*256 + ks*32 + lk*8);
                acc[ct] = __builtin_amdgcn_mfma_f32_16x16x32_f16(a[ks], bf, acc[ct], 0,0,0);
            }
        }
        #pragma unroll
        for (int ct=0; ct<4; ct++){
            #pragma unroll
            for (int i=0;i<4;i++)
                lds[w][(lk4+i)*72 + ct*16 + lr] = __float2half(acc[ct][i]);
        }
        __half* base = (cg == 0) ? xl2h : xr2h;
        #pragma unroll
        for (int rr=0; rr<2; rr++){
            int row = rr*8 + (l>>3);
            float4 v = *(const float4*)&lds[w][row*72 + (l&7)*8];
            int grow = r0 + row;
            if (grow < N_NODES)
                *(float4*)&base[(size_t)grow*64 + (l&7)*8] = v;
        }
    }
}

// ---- fused GAT layer 1: wave per node, 4/block. 32 lanes/edge x 8 ch;
// 4 edges in flight/slot-group. fp16 accumulate held across 16 edges
// (2 iters) before f32 flush; bound 16*e_max*|v|max ~ 1.3e4 << 65504.
__global__ __launch_bounds__(256) void k_gat1(const __half* __restrict__ xlh,
        const __half* __restrict__ xrh, const int* __restrict__ srcs,
        const int* __restrict__ rowptr, const float* __restrict__ att,
        const float* __restrict__ b, __half* __restrict__ h1h){
    int w = threadIdx.x >> 6, l = threadIdx.x & 63;
    int n = blockIdx.x*4 + w;
    int g = l >> 5, sub = l & 31;
    const float4* xh4 = (const float4*)xlh;   // 32 f4 per row
    float4 rq = *(const float4*)(xrh + (size_t)n*256 + sub*8);
    __half2 r2[4];
    { const __half2* rh = (const __half2*)&rq;
      r2[0]=rh[0]; r2[1]=rh[1]; r2[2]=rh[2]; r2[3]=rh[3]; }
    float4 A0v = *(const float4*)(att + sub*8);
    float4 A1v = *(const float4*)(att + sub*8 + 4);
    const float C6 = 0.6f*L2E, C4 = 0.4f*L2E;
    __half2 A6[4] = { __floats2half2_rn(A0v.x*C6, A0v.y*C6),
                      __floats2half2_rn(A0v.z*C6, A0v.w*C6),
                      __floats2half2_rn(A1v.x*C6, A1v.y*C6),
                      __floats2half2_rn(A1v.z*C6, A1v.w*C6) };
    __half2 A4[4] = { __floats2half2_rn(A0v.x*C4, A0v.y*C4),
                      __floats2half2_rn(A0v.z*C4, A0v.w*C4),
                      __floats2half2_rn(A1v.x*C4, A1v.y*C4),
                      __floats2half2_rn(A1v.z*C4, A1v.w*C4) };
    const __half2 Z2 = __floats2half2_rn(0.f, 0.f);
    float accf[8];
    #pragma unroll
    for (int c=0;c<8;c++) accf[c]=0.f;
    __half2 a16[4] = {Z2, Z2, Z2, Z2};
    float dacc = 0.f;
    int beg = rowptr[n], end = rowptr[n+1];

    auto body = [&](int j, bool checked){
        int j0=j+g, j1=j+2+g, j2=j+4+g, j3=j+6+g;
        bool c0=true, c1=true, c2=true, c3=true;
        if (checked){
            c0 = j0<end; c1 = j1<end; c2 = j2<end; c3 = j3<end;
            j0 = c0?j0:beg; j1 = c1?j1:beg; j2 = c2?j2:beg; j3 = c3?j3:beg;
        }
        int s0 = srcs[j0], s1 = srcs[j1], s2 = srcs[j2], s3 = srcs[j3];
        float4 q0 = xh4[(unsigned)(s0*32 + sub)];
        float4 q1 = xh4[(unsigned)(s1*32 + sub)];
        float4 q2 = xh4[(unsigned)(s2*32 + sub)];
        float4 q3 = xh4[(unsigned)(s3*32 + sub)];
        float p0 = pkdot(q0, r2, A6, A4);
        float p1 = pkdot(q1, r2, A6, A4);
        float p2 = pkdot(q2, r2, A6, A4);
        float p3 = pkdot(q3, r2, A6, A4);
        #pragma unroll
        for (int off=1; off<8; off<<=1){
            p0 += __shfl_xor(p0, off);
            p1 += __shfl_xor(p1, off);
            p2 += __shfl_xor(p2, off);
            p3 += __shfl_xor(p3, off);
        }
        float e0 = exp2f(p0), e1 = exp2f(p1), e2 = exp2f(p2), e3 = exp2f(p3);
        if (checked){
            e0 = c0?e0:0.f; e1 = c1?e1:0.f; e2 = c2?e2:0.f; e3 = c3?e3:0.f;
        }
        __half2 E0 = bcast_h2(e0);
        __half2 E1 = bcast_h2(e1);
        __half2 E2 = bcast_h2(e2);
        __half2 E3 = bcast_h2(e3);
        const __half2* q0h = (const __half2*)&q0;
        const __half2* q1h = (const __half2*)&q1;
        const __half2* q2h = (const __half2*)&q2;
        const __half2* q3h = (const __half2*)&q3;
        #pragma unroll
        for (int i=0;i<4;i++){
            a16[i] = __hfma2(E0, q0h[i], a16[i]);
            a16[i] = __hfma2(E1, q1h[i], a16[i]);
            a16[i] = __hfma2(E2, q2h[i], a16[i]);
            a16[i] = __hfma2(E3, q3h[i], a16[i]);
        }
        dacc += e0 + e1 + e2 + e3;
    };
    auto flush = [&](){
        #pragma unroll
        for (int i=0;i<4;i++){
            float2 f = __half22float2(a16[i]);
            accf[2*i]   += f.x;
            accf[2*i+1] += f.y;
            a16[i] = Z2;
        }
    };

    int j = beg;
    int nfull = (end - beg) >> 3;
    int it = 0;
    for (; it+2<=nfull; it+=2){
        body(j, false); j += 8;
        body(j, false); j += 8;
        flush();
    }
    if (it < nfull){ body(j, false); j += 8; }
    if (j < end) body(j, true);
    flush();

    #pragma unroll
    for (int c=0;c<8;c++) accf[c] += __shfl_xor(accf[c], 32);
    dacc += __shfl_xor(dacc, 32);
    if (l < 32){
        float inv = 1.f / (dacc + 1e-16f);
        float4 B0 = *(const float4*)(b + l*8);
        float4 B1 = *(const float4*)(b + l*8 + 4);
        float4 st;
        __half2* sp = (__half2*)&st;
        sp[0] = __floats2half2_rn(elu1(fmaf(accf[0],inv,B0.x)), elu1(fmaf(accf[1],inv,B0.y)));
        sp[1] = __floats2half2_rn(elu1(fmaf(accf[2],inv,B0.z)), elu1(fmaf(accf[3],inv,B0.w)));
        sp[2] = __floats2half2_rn(elu1(fmaf(accf[4],inv,B1.x)), elu1(fmaf(accf[5],inv,B1.y)));
        sp[3] = __floats2half2_rn(elu1(fmaf(accf[6],inv,B1.z)), elu1(fmaf(accf[7],inv,B1.w)));
        *(float4*)(h1h + (size_t)n*256 + l*8) = st;
    }
}

// ---- fused GAT layer 2: wave per node; 8 lanes/edge x 8 ch; 16 edges in
// flight. h2 out fp16.
__global__ __launch_bounds__(256) void k_gat2(const __half* __restrict__ xlh,
        const __half* __restrict__ xrh, const int* __restrict__ srcs,
        const int* __restrict__ rowptr, const float* __restrict__ att,
        const float* __restrict__ b, __half* __restrict__ h2h){
    int w = threadIdx.x >> 6, l = threadIdx.x & 63;
    int n = blockIdx.x*4 + w;
    int g = l >> 3, sub = l & 7;
    const float4* xh4 = (const float4*)xlh;   // 8 f4 per row
    float4 rq = *(const float4*)(xrh + (size_t)n*64 + sub*8);
    __half2 r2[4];
    { const __half2* rh = (const __half2*)&rq;
      r2[0]=rh[0]; r2[1]=rh[1]; r2[2]=rh[2]; r2[3]=rh[3]; }
    float4 A0v = *(const float4*)(att + sub*8);
    float4 A1v = *(const float4*)(att + sub*8 + 4);
    const float C6 = 0.6f*L2E, C4 = 0.4f*L2E;
    __half2 A6[4] = { __floats2half2_rn(A0v.x*C6, A0v.y*C6),
                      __floats2half2_rn(A0v.z*C6, A0v.w*C6),
                      __floats2half2_rn(A1v.x*C6, A1v.y*C6),
                      __floats2half2_rn(A1v.z*C6, A1v.w*C6) };
    __half2 A4[4] = { __floats2half2_rn(A0v.x*C4, A0v.y*C4),
                      __floats2half2_rn(A0v.z*C4, A0v.w*C4),
                      __floats2half2_rn(A1v.x*C4, A1v.y*C4),
                      __floats2half2_rn(A1v.z*C4, A1v.w*C4) };
    const __half2 Z2 = __floats2half2_rn(0.f, 0.f);
    __half2 a16[4] = {Z2, Z2, Z2, Z2};
    float dacc = 0.f;
    int beg = rowptr[n], end = rowptr[n+1];

    auto body = [&](int j, bool checked){
        int j0 = j+g, j1 = j+8+g;
        bool c0=true, c1=true;
        if (checked){
            c0 = j0<end; c1 = j1<end;
            j0 = c0?j0:beg; j1 = c1?j1:beg;
        }
        int s0 = srcs[j0], s1 = srcs[j1];
        float4 q0 = xh4[(unsigned)(s0*8 + sub)];
        float4 q1 = xh4[(unsigned)(s1*8 + sub)];
        float p0 = pkdot(q0, r2, A6, A4);
        float p1 = pkdot(q1, r2, A6, A4);
        #pragma unroll
        for (int off=1; off<8; off<<=1){
            p0 += __shfl_xor(p0, off);
            p1 += __shfl_xor(p1, off);
        }
        float e0 = exp2f(p0), e1 = exp2f(p1);
        if (checked){ e0 = c0?e0:0.f; e1 = c1?e1:0.f; }
        __half2 E0 = bcast_h2(e0);
        __half2 E1 = bcast_h2(e1);
        const __half2* q0h = (const __half2*)&q0;
        const __half2* q1h = (const __half2*)&q1;
        #pragma unroll
        for (int i=0;i<4;i++){
            a16[i] = __hfma2(E0, q0h[i], a16[i]);
            a16[i] = __hfma2(E1, q1h[i], a16[i]);
        }
        dacc += e0 + e1;
    };

    int j = beg;
    int nfull = (end - beg) >> 4;
    for (int it=0; it<nfull; ++it, j+=16) body(j, false);
    if (j < end) body(j, true);

    float accf[8];
    #pragma unroll
    for (int i=0;i<4;i++){
        float2 f = __half22float2(a16[i]);
        accf[2*i] = f.x; accf[2*i+1] = f.y;
    }
    #pragma unroll
    for (int off=8; off<64; off<<=1){
        #pragma unroll
        for (int c=0;c<8;c++) accf[c] += __shfl_xor(accf[c], off);
        dacc += __shfl_xor(dacc, off);
    }
    if (l < 8){
        float inv = 1.f / (dacc + 1e-16f);
        float4 B0 = *(const float4*)(b + l*8);
        float4 B1 = *(const float4*)(b + l*8 + 4);
        float4 st;
        __half2* sp = (__half2*)&st;
        sp[0] = __floats2half2_rn(elu1(fmaf(accf[0],inv,B0.x)), elu1(fmaf(accf[1],inv,B0.y)));
        sp[1] = __floats2half2_rn(elu1(fmaf(accf[2],inv,B0.z)), elu1(fmaf(accf[3],inv,B0.w)));
        sp[2] = __floats2half2_rn(elu1(fmaf(accf[4],inv,B1.x)), elu1(fmaf(accf[5],inv,B1.y)));
        sp[3] = __floats2half2_rn(elu1(fmaf(accf[6],inv,B1.z)), elu1(fmaf(accf[7],inv,B1.w)));
        *(float4*)(h2h + (size_t)n*64 + l*8) = st;
    }
}

__device__ __forceinline__ int lower_bound_i(const int* a, int n, int key){
    int lo = 0, hi = n;
    while (lo < hi){ int mid = (lo+hi)>>1; if (a[mid] < key) lo = mid+1; else hi = mid; }
    return lo;
}

// ---- mean pool over fp16 h2: grid (64 graphs, 8 parts); lane = channel-pair
__global__ __launch_bounds__(256) void k_pool(const __half* __restrict__ h2h,
        const int* __restrict__ batch, float* __restrict__ pooled){
    int gph = blockIdx.x, part = blockIdx.y;
    int t = threadIdx.x, c2 = t & 31, q = t >> 5;     // 32 ch-pairs x 8 rows
    int start = lower_bound_i(batch, N_NODES, gph);
    int end   = lower_bound_i(batch, N_NODES, gph+1);
    int len = end - start;
    int is = start + (int)(((long long)len*part) >> 3);
    int ie = start + (int)(((long long)len*(part+1)) >> 3);
    float2 s = make_float2(0.f, 0.f);
    const __half2* h22 = (const __half2*)h2h;
    for (int i = is + q; i < ie; i += 8){
        float2 f = __half22float2(h22[(unsigned)(i*32 + c2)]);
        s.x += f.x; s.y += f.y;
    }
    __shared__ float2 red[256];
    red[t] = s; __syncthreads();
    if (q == 0){
        float2 tot = red[c2];
        #pragma unroll
        for (int qq=1; qq<8; qq++){
            tot.x += red[qq*32 + c2].x;
            tot.y += red[qq*32 + c2].y;
        }
        atomicAdd(&pooled[gph*64 + c2*2],     tot.x);
        atomicAdd(&pooled[gph*64 + c2*2 + 1], tot.y);
    }
}

// ---- MLP head (pooled sums -> mean -> 64 -> relu -> 2)
__global__ __launch_bounds__(64) void k_mlp(const float* __restrict__ pooled,
        const int* __restrict__ batch,
        const float* __restrict__ W3, const float* __restrict__ b3,
        const float* __restrict__ W4, const float* __restrict__ b4,
        float* __restrict__ out){
    int gph = blockIdx.x, t = threadIdx.x;
    __shared__ float ps[64], zs[64];
    int start = lower_bound_i(batch, N_NODES, gph);
    int end   = lower_bound_i(batch, N_NODES, gph+1);
    float cnt = fmaxf((float)(end - start), 1.f);
    ps[t] = pooled[gph*64 + t] / cnt;
    __syncthreads();
    float a = b3[t];
    for (int k=0;k<64;k++) a = fmaf(ps[k], W3[k*64+t], a);
    zs[t] = fmaxf(a, 0.f); __syncthreads();
    if (t < 2){
        float o = b4[t];
        for (int k=0;k<64;k++) o = fmaf(zs[k], W4[k*2+t], o);
        out[gph*2 + t] = o;
    }
}

extern "C" void kernel_launch(void* const* d_in, const int* in_sizes, int n_in,
                              void* d_out, int out_size, void* d_ws, size_t ws_size,
                              hipStream_t stream) {
    const float* x    = (const float*)d_in[0];
    const int*   ei   = (const int*)  d_in[1];   // [2, E] flat
    const int*   batch= (const int*)  d_in[2];
    const float* Wl1  = (const float*)d_in[3];
    const float* Wr1  = (const float*)d_in[4];
    const float* att1 = (const float*)d_in[5];
    const float* b1   = (const float*)d_in[6];
    const float* Wl2  = (const float*)d_in[7];
    const float* Wr2  = (const float*)d_in[8];
    const float* att2 = (const float*)d_in[9];
    const float* b2   = (const float*)d_in[10];
    const float* W3   = (const float*)d_in[11];
    const float* b3   = (const float*)d_in[12];
    const float* W4   = (const float*)d_in[13];
    const float* b4   = (const float*)d_in[14];
    float* out = (float*)d_out;

    // workspace layout
    char* wsp = (char*)d_ws;
    size_t off = 0;
    auto alloc = [&](size_t bytes) -> char* {
        char* p = wsp + off; off += (bytes + 255) & ~(size_t)255; return p;
    };
    __half* xh    = (__half*)alloc((size_t)N_NODES*64*2);     // 6.4 MB
    __half* Wt1   = (__half*)alloc(512*64*2);                 // [col][k]
    __half* Wt2   = (__half*)alloc(128*256*2);                // [col][k]
    __half* xl1h  = (__half*)alloc((size_t)N_NODES*256*2);    // 25.6 MB
    __half* xr1h  = (__half*)alloc((size_t)N_NODES*256*2);    // 25.6 MB
    __half* h1h   = (__half*)alloc((size_t)N_NODES*256*2);    // 25.6 MB
    int* rowptr   = (int*)alloc((N_NODES+1)*4);
    int* partial  = (int*)alloc(64*4);
    int* srcs     = (int*)alloc((size_t)N_EDGES*4);
    int* ranks    = (int*)alloc((size_t)N_EDGES*4);
    int* deg8     = (int*)alloc((size_t)NPART*NPAD*4);        // 1.6 MB
    int* off8     = (int*)alloc((size_t)NPART*NPAD*4);        // 1.6 MB
    float* pooled = (float*)alloc(N_GRAPHS*64*4);
    // overlays (dead-region reuse after k_gat1)
    __half* xl2h  = xl1h;                                     // [N,64] fp16
    __half* xr2h  = xl1h + (size_t)N_NODES*64;                // [N,64] fp16
    __half* h2h   = (__half*)xr1h;                            // [N,64] fp16

    hipMemsetAsync(deg8, 0, (size_t)NPART*NPAD*sizeof(int), stream);
    k_prep<<<782+3125+256, 256, 0, stream>>>(x, Wl1, Wr1, Wl2, Wr2, ei,
                                             xh, Wt1, Wt2, deg8, ranks, pooled);
    k_scan_a<<<49, 1024, 0, stream>>>(deg8, off8, rowptr, partial);
    k_scan_c<<<49, 1024, 0, stream>>>(rowptr, partial);

    k_mm1<<<dim3(782,2), 256, 0, stream>>>(xh, Wt1, xl1h, xr1h,
                                           ei, ranks, rowptr, off8, srcs);
    k_gat1<<<N_NODES/4, 256, 0, stream>>>(xl1h, xr1h, srcs, rowptr, att1, b1, h1h);
    k_mm2<<<782, 256, 0, stream>>>(h1h, Wt2, xl2h, xr2h);
    k_gat2<<<N_NODES/4, 256, 0, stream>>>(xl2h, xr2h, srcs, rowptr, att2, b2, h2h);
    k_pool<<<dim3(N_GRAPHS,8), 256, 0, stream>>>(h2h, batch, pooled);
    k_mlp<<<N_GRAPHS, 64, 0, stream>>>(pooled, batch, W3, b3, W4, b4, out);
}